// Round 11
// baseline (142.937 us; speedup 1.0000x reference)
//
#include <hip/hip_runtime.h>
#include <hip/hip_bf16.h>

constexpr int N_NODES = 100000;
constexpr int N_EDGES = 1600000;
constexpr int IN_DIM  = 128;
constexpr int HID_DIM = 64;
constexpr int OUT_DIM = 40;

constexpr int BK_SHIFT = 9;                           // 512-node coarse buckets
constexpr int NBKT = (N_NODES + 511) >> 9;            // 196
constexpr int ECAP = 9216;                            // mean 8192, +11 sigma
constexpr int TILE = 4096;
constexpr int EPT  = TILE / 256;                      // 16 edges per thread
constexpr int NTILES = (N_EDGES + TILE - 1) / TILE;   // 391
constexpr int GEMM_BLK = (N_NODES + 63) / 64;         // 1563

typedef __attribute__((ext_vector_type(8))) short short8;
typedef __attribute__((ext_vector_type(4))) float f32x4;

__device__ inline float bf2f(unsigned int u16) {
  union { float f; unsigned int i; } c;
  c.i = u16 << 16;
  return c.f;
}

__device__ inline unsigned short f2bf(float f) {
  union { float f; unsigned int u; } c; c.f = f;
  unsigned int u = c.u + 0x7fffu + ((c.u >> 16) & 1u);
  return (unsigned short)(u >> 16);
}

// init: zero bucket cursors + build W1/W2 MFMA B-fragments (bf16). Grid-strided.
__global__ void k_init(const float* __restrict__ W1, const float* __restrict__ W2,
                       unsigned short* __restrict__ Bfrag1, unsigned short* __restrict__ Bfrag2,
                       int* __restrict__ gcur) {
  int tid = blockIdx.x * blockDim.x + threadIdx.x;
  int stride = gridDim.x * blockDim.x;
  for (int i = tid; i < 2 * NBKT; i += stride) gcur[i] = 0;
  for (int idx = tid; idx < 4 * 4 * 64 * 8; idx += stride) {
    int j = idx & 7;
    int lane = (idx >> 3) & 63;
    int nt = (idx >> 9) & 3;
    int ks = idx >> 11;
    int k = ks * 32 + 8 * (lane >> 4) + j;
    int col = nt * 16 + (lane & 15);
    Bfrag1[idx] = f2bf(W1[k * HID_DIM + col]);
  }
  for (int idx = tid; idx < 2 * 3 * 64 * 8; idx += stride) {
    int j = idx & 7;
    int lane = (idx >> 3) & 63;
    int nt = (idx >> 9) % 3;
    int ks = idx / (3 * 512);
    int k = ks * 32 + 8 * (lane >> 4) + j;
    int col = nt * 16 + (lane & 15);
    Bfrag2[idx] = (col < OUT_DIM) ? f2bf(W2[k * OUT_DIM + col]) : (unsigned short)0;
  }
}

// Fused partition: packed (ldst<<17|src) by dst>>9  AND  (src&511) by src>>9.
__global__ __launch_bounds__(256) void k_part(const int* __restrict__ src,
                                              const int* __restrict__ dst,
                                              int* __restrict__ gcur,
                                              int* __restrict__ gcur2,
                                              unsigned int* __restrict__ pairs,
                                              unsigned short* __restrict__ spart) {
  __shared__ int scnt[NBKT], soff[NBKT], gbase[NBKT];
  __shared__ int scnt2[NBKT], soff2[NBKT], gbase2[NBKT];
  __shared__ int sc1[256], sc2[256];
  __shared__ unsigned int sord[TILE];           // 16 KB packed pair
  __shared__ unsigned char sordB[TILE];         // 4 KB bucket id
  __shared__ unsigned short sordS[TILE];        // 8 KB local src idx
  __shared__ unsigned char sordSB[TILE];        // 4 KB bucket id
  int tid = threadIdx.x;
  int tileBase = blockIdx.x * TILE;
  int tcnt = N_EDGES - tileBase; if (tcnt > TILE) tcnt = TILE;
  if (tid < NBKT) { scnt[tid] = 0; scnt2[tid] = 0; }
  __syncthreads();
  int s_[EPT], d_[EPT], pos_[EPT], pos2_[EPT];
#pragma unroll
  for (int t = 0; t < EPT; ++t) {
    int idx = tileBase + t * 256 + tid;
    if (idx < N_EDGES) {
      s_[t] = src[idx];
      d_[t] = dst[idx];
      pos_[t]  = atomicAdd(&scnt[d_[t] >> BK_SHIFT], 1);
      pos2_[t] = atomicAdd(&scnt2[s_[t] >> BK_SHIFT], 1);
    }
  }
  __syncthreads();
  // parallel exclusive scan of both count arrays (NBKT <= 256)
  int v1 = (tid < NBKT) ? scnt[tid] : 0;
  int v2 = (tid < NBKT) ? scnt2[tid] : 0;
  sc1[tid] = v1; sc2[tid] = v2;
  __syncthreads();
  for (int o = 1; o < 256; o <<= 1) {
    int x1 = (tid >= o) ? sc1[tid - o] : 0;
    int x2 = (tid >= o) ? sc2[tid - o] : 0;
    __syncthreads();
    sc1[tid] += x1; sc2[tid] += x2;
    __syncthreads();
  }
  if (tid < NBKT) {
    soff[tid]  = sc1[tid] - v1;
    soff2[tid] = sc2[tid] - v2;
    gbase[tid]  = v1 ? atomicAdd(&gcur[tid],  v1) : 0;
    gbase2[tid] = v2 ? atomicAdd(&gcur2[tid], v2) : 0;
  }
  __syncthreads();
#pragma unroll
  for (int t = 0; t < EPT; ++t) {
    int idx = tileBase + t * 256 + tid;
    if (idx < N_EDGES) {
      int b  = d_[t] >> BK_SHIFT;
      int b2 = s_[t] >> BK_SHIFT;
      int p  = soff[b] + pos_[t];
      int p2 = soff2[b2] + pos2_[t];
      sord[p]  = (unsigned)s_[t] | ((unsigned)(d_[t] & 511) << 17);
      sordB[p] = (unsigned char)b;
      sordS[p2]  = (unsigned short)(s_[t] & 511);
      sordSB[p2] = (unsigned char)b2;
    }
  }
  __syncthreads();
  for (int i = tid; i < tcnt; i += 256) {
    int b = sordB[i];
    int g = gbase[b] + (i - soff[b]);
    if (g < ECAP) pairs[(size_t)b * ECAP + g] = sord[i];
  }
  for (int i = tid; i < tcnt; i += 256) {
    int b = sordSB[i];
    int g = gbase2[b] + (i - soff2[b]);
    if (g < ECAP) spart[(size_t)b * ECAP + g] = sordS[i];
  }
}

// Merged mid kernel:
//   blocks [0,NBKT)        : fine CSR (startg, cntg, norm_dst, esrc)
//   blocks [NBKT,2*NBKT)   : out-degree histogram -> norm_src
//   blocks [2*NBKT, +GEMM_BLK): MFMA GEMM1, t1 = bf16(feats @ W1)  (NO norm_src)
__global__ __launch_bounds__(256) void k_mid(const unsigned int* __restrict__ pairs,
                                             const unsigned short* __restrict__ spart,
                                             const int* __restrict__ gcur,
                                             const int* __restrict__ gcur2,
                                             int* __restrict__ startg,
                                             int* __restrict__ cntg,
                                             float* __restrict__ norm_dst,
                                             float* __restrict__ norm_src,
                                             int* __restrict__ esrc,
                                             const float* __restrict__ feats,
                                             const uint4* __restrict__ Bfrag1,
                                             __hip_bfloat16* __restrict__ t1) {
  __shared__ int cnt[512];
  __shared__ int off[512];
  __shared__ int cur[512];
  __shared__ int wsum[256];
  __shared__ int esrcL[ECAP];   // 36 KB
  int tid = threadIdx.x;
  int bx = blockIdx.x;

  if (bx >= 2 * NBKT) {
    // ---- GEMM1 branch ----
    int blk = bx - 2 * NBKT;
    int w = tid >> 6, lane = tid & 63;
    int row0 = blk * 64 + w * 16;
    int arow = row0 + (lane & 15);
    int arowc = arow < N_NODES ? arow : N_NODES - 1;
    int half = lane >> 4;
    const float4* fr = (const float4*)(feats + (size_t)arowc * IN_DIM);
    f32x4 acc[4] = {{0.f,0.f,0.f,0.f},{0.f,0.f,0.f,0.f},{0.f,0.f,0.f,0.f},{0.f,0.f,0.f,0.f}};
#pragma unroll
    for (int ks = 0; ks < 4; ++ks) {
      float4 p0 = fr[ks * 8 + 2 * half];
      float4 p1 = fr[ks * 8 + 2 * half + 1];
      short8 a;
      a[0] = (short)f2bf(p0.x); a[1] = (short)f2bf(p0.y);
      a[2] = (short)f2bf(p0.z); a[3] = (short)f2bf(p0.w);
      a[4] = (short)f2bf(p1.x); a[5] = (short)f2bf(p1.y);
      a[6] = (short)f2bf(p1.z); a[7] = (short)f2bf(p1.w);
#pragma unroll
      for (int nt = 0; nt < 4; ++nt) {
        uint4 bu = Bfrag1[(ks * 4 + nt) * 64 + lane];
        short8 b = *(const short8*)&bu;
        acc[nt] = __builtin_amdgcn_mfma_f32_16x16x32_bf16(a, b, acc[nt], 0, 0, 0);
      }
    }
    int col = lane & 15;
    int rbase = row0 + half * 4;
#pragma unroll
    for (int r = 0; r < 4; ++r) {
      int grow = rbase + r;
      if (grow < N_NODES) {
#pragma unroll
        for (int nt = 0; nt < 4; ++nt) {
          unsigned short h = f2bf(acc[nt][r]);
          *((unsigned short*)t1 + (size_t)grow * HID_DIM + nt * 16 + col) = h;
        }
      }
    }
    return;
  }

  if (bx >= NBKT) {
    // ---- out-degree histogram -> norm_src ----
    int b = bx - NBKT;
    int node0 = b << BK_SHIFT;
    int nNodes = N_NODES - node0; if (nNodes > 512) nNodes = 512;
    int E = gcur2[b]; if (E > ECAP) E = ECAP;
    cnt[tid] = 0; cnt[tid + 256] = 0;
    __syncthreads();
    const unsigned short* sp = spart + (size_t)b * ECAP;
    for (int i = tid; i < E; i += 256) atomicAdd(&cnt[sp[i]], 1);
    __syncthreads();
    for (int j = tid; j < nNodes; j += 256) {
      int c = cnt[j];
      norm_src[node0 + j] = rsqrtf((float)(c < 1 ? 1 : c));
    }
    return;
  }

  // ---- fine CSR ----
  int b = bx;
  int node0 = b << BK_SHIFT;
  int nNodes = N_NODES - node0; if (nNodes > 512) nNodes = 512;
  int E = gcur[b]; if (E > ECAP) E = ECAP;
  cnt[tid] = 0; cnt[tid + 256] = 0;
  __syncthreads();
  const unsigned int* pp = pairs + (size_t)b * ECAP;
  for (int i = tid; i < E; i += 256) atomicAdd(&cnt[pp[i] >> 17], 1);
  __syncthreads();
  int v0 = cnt[tid * 2], v1 = cnt[tid * 2 + 1];
  int s = v0 + v1;
  wsum[tid] = s; __syncthreads();
  for (int o = 1; o < 256; o <<= 1) {
    int x = (tid >= o) ? wsum[tid - o] : 0;
    __syncthreads();
    wsum[tid] += x;
    __syncthreads();
  }
  int excl = wsum[tid] - s;
  off[tid * 2] = excl;     cur[tid * 2] = excl;
  off[tid * 2 + 1] = excl + v0; cur[tid * 2 + 1] = excl + v0;
  __syncthreads();
  for (int i = tid; i < E; i += 256) {
    unsigned p = pp[i];
    int pos = atomicAdd(&cur[p >> 17], 1);
    esrcL[pos] = (int)(p & 0x1FFFFu);
  }
  __syncthreads();
  int base = b * ECAP;
  for (int i = tid; i < E; i += 256) esrc[base + i] = esrcL[i];
  for (int j = tid; j < nNodes; j += 256) {
    int c = cnt[j];
    startg[node0 + j] = base + off[j];
    cntg[node0 + j] = c;
    norm_dst[node0 + j] = rsqrtf((float)(c < 1 ? 1 : c));
  }
}

// Fused layer-1 gather + layer-2 GEMM.
// 32 nodes/block, 8 lanes per node, each lane owns 8 bf16 cols (uint4 = 16 B).
// norm_src applied per-edge (t1 is un-normalized).
__global__ __launch_bounds__(256) void k_agg1g2(
    const uint4* __restrict__ t1, const int* __restrict__ startg,
    const int* __restrict__ cntg, const int* __restrict__ esrc,
    const float* __restrict__ norm_dst, const float* __restrict__ norm_src,
    const float4* __restrict__ b1v, const uint4* __restrict__ Bfrag2,
    float4* __restrict__ out1, __hip_bfloat16* __restrict__ t2) {
  __shared__ unsigned short h1s[32][64];   // 4 KB bf16 A-tile
  int tid = threadIdx.x;
  int g = tid >> 3, q = tid & 7;
  int n = blockIdx.x * 32 + g;          // 100000 = 3125*32 exact
  int s0 = startg[n];
  int c  = cntg[n];
  const int* bk = esrc + s0;
  float a0 = 0.f, a1 = 0.f, a2 = 0.f, a3 = 0.f;
  float a4 = 0.f, a5 = 0.f, a6 = 0.f, a7 = 0.f;
  for (int i = 0; i < c; i += 8) {
#pragma unroll
    for (int t = 0; t < 8; ++t) {
      int ii = i + t;
      bool ok = ii < c;
      int s = bk[ok ? ii : 0];
      float nss = ok ? norm_src[s] : 0.f;
      uint4 v = t1[(size_t)s * 8 + q];
      a0 += nss * bf2f(v.x & 0xffffu); a1 += nss * bf2f(v.x >> 16);
      a2 += nss * bf2f(v.y & 0xffffu); a3 += nss * bf2f(v.y >> 16);
      a4 += nss * bf2f(v.z & 0xffffu); a5 += nss * bf2f(v.z >> 16);
      a6 += nss * bf2f(v.w & 0xffffu); a7 += nss * bf2f(v.w >> 16);
    }
  }
  float nd = norm_dst[n];
  float4 bb0 = b1v[q * 2];
  float4 bb1 = b1v[q * 2 + 1];
  float h0 = fmaxf(a0 * nd + bb0.x, 0.f);
  float h1 = fmaxf(a1 * nd + bb0.y, 0.f);
  float h2 = fmaxf(a2 * nd + bb0.z, 0.f);
  float h3 = fmaxf(a3 * nd + bb0.w, 0.f);
  float h4 = fmaxf(a4 * nd + bb1.x, 0.f);
  float h5 = fmaxf(a5 * nd + bb1.y, 0.f);
  float h6 = fmaxf(a6 * nd + bb1.z, 0.f);
  float h7 = fmaxf(a7 * nd + bb1.w, 0.f);
  out1[(size_t)n * 16 + q * 2]     = make_float4(h0, h1, h2, h3);
  out1[(size_t)n * 16 + q * 2 + 1] = make_float4(h4, h5, h6, h7);
  float ns = norm_src[n];
  uint4 pk;
  pk.x = (unsigned)f2bf(h0 * ns) | ((unsigned)f2bf(h1 * ns) << 16);
  pk.y = (unsigned)f2bf(h2 * ns) | ((unsigned)f2bf(h3 * ns) << 16);
  pk.z = (unsigned)f2bf(h4 * ns) | ((unsigned)f2bf(h5 * ns) << 16);
  pk.w = (unsigned)f2bf(h6 * ns) | ((unsigned)f2bf(h7 * ns) << 16);
  *(uint4*)&h1s[g][q * 8] = pk;
  __syncthreads();
  if (tid < 128) {
    int wave = tid >> 6;
    int lane = tid & 63;
    int r = lane & 15, half = lane >> 4;
    int row = wave * 16 + r;
    f32x4 acc[3] = {{0.f,0.f,0.f,0.f},{0.f,0.f,0.f,0.f},{0.f,0.f,0.f,0.f}};
#pragma unroll
    for (int ks = 0; ks < 2; ++ks) {
      short8 a = *(const short8*)&h1s[row][ks * 32 + 8 * half];
#pragma unroll
      for (int nt = 0; nt < 3; ++nt) {
        uint4 bu = Bfrag2[(ks * 3 + nt) * 64 + lane];
        short8 b = *(const short8*)&bu;
        acc[nt] = __builtin_amdgcn_mfma_f32_16x16x32_bf16(a, b, acc[nt], 0, 0, 0);
      }
    }
    int col = lane & 15;
#pragma unroll
    for (int r2 = 0; r2 < 4; ++r2) {
      int node = blockIdx.x * 32 + wave * 16 + half * 4 + r2;
#pragma unroll
      for (int nt = 0; nt < 3; ++nt) {
        int j = nt * 16 + col;
        if (j < OUT_DIM)
          *((unsigned short*)t2 + (size_t)node * OUT_DIM + j) = f2bf(acc[nt][r2]);
      }
    }
  }
}

// Layer-2 gather: 5 lanes per node, each lane owns 8 bf16 cols (uint4 = 16 B).
__global__ __launch_bounds__(256) void k_agg2(
    const uint4* __restrict__ t2, const int* __restrict__ startg,
    const int* __restrict__ cntg, const int* __restrict__ esrc,
    const float* __restrict__ norm_dst, const float* __restrict__ b2,
    float4* __restrict__ out2) {
  int idx = blockIdx.x * blockDim.x + threadIdx.x;
  int n = idx / 5;
  int q = idx - n * 5;
  if (n >= N_NODES) return;
  int s0 = startg[n];
  int c  = cntg[n];
  const int* bk = esrc + s0;
  float a0 = 0.f, a1 = 0.f, a2 = 0.f, a3 = 0.f;
  float a4 = 0.f, a5 = 0.f, a6 = 0.f, a7 = 0.f;
  for (int i = 0; i < c; i += 8) {
#pragma unroll
    for (int t = 0; t < 8; ++t) {
      int ii = i + t;
      bool ok = ii < c;
      int s = bk[ok ? ii : 0];
      uint4 v = t2[(size_t)s * 5 + q];
      unsigned vx = ok ? v.x : 0u;
      unsigned vy = ok ? v.y : 0u;
      unsigned vz = ok ? v.z : 0u;
      unsigned vw = ok ? v.w : 0u;
      a0 += bf2f(vx & 0xffffu); a1 += bf2f(vx >> 16);
      a2 += bf2f(vy & 0xffffu); a3 += bf2f(vy >> 16);
      a4 += bf2f(vz & 0xffffu); a5 += bf2f(vz >> 16);
      a6 += bf2f(vw & 0xffffu); a7 += bf2f(vw >> 16);
    }
  }
  float nd = norm_dst[n];
  float4 bb0 = *(const float4*)(b2 + q * 8);
  float4 bb1 = *(const float4*)(b2 + q * 8 + 4);
  out2[(size_t)n * 10 + q * 2] =
      make_float4(a0 * nd + bb0.x, a1 * nd + bb0.y, a2 * nd + bb0.z, a3 * nd + bb0.w);
  out2[(size_t)n * 10 + q * 2 + 1] =
      make_float4(a4 * nd + bb1.x, a5 * nd + bb1.y, a6 * nd + bb1.z, a7 * nd + bb1.w);
}

extern "C" void kernel_launch(void* const* d_in, const int* in_sizes, int n_in,
                              void* d_out, int out_size, void* d_ws, size_t ws_size,
                              hipStream_t stream) {
  const float* feats = (const float*)d_in[0];
  const float* W1    = (const float*)d_in[1];
  const float* b1    = (const float*)d_in[2];
  const float* W2    = (const float*)d_in[3];
  const float* b2    = (const float*)d_in[4];
  const int*   src   = (const int*)d_in[5];
  const int*   dst   = (const int*)d_in[6];

  float* out  = (float*)d_out;
  float* out1 = out;                                  // [N, 64]
  float* out2 = out + (size_t)N_NODES * HID_DIM;      // [N, 40]

  __hip_bfloat16* t1 = (__hip_bfloat16*)d_ws;                 // 12.8 MB
  __hip_bfloat16* t2 = t1 + (size_t)N_NODES * HID_DIM;        //  8.0 MB
  unsigned int* pairs = (unsigned int*)(t2 + (size_t)N_NODES * OUT_DIM);   // 7.22 MB
  unsigned short* spart = (unsigned short*)(pairs + (size_t)NBKT * ECAP);  // 3.61 MB
  int* esrc   = (int*)(spart + (size_t)NBKT * ECAP);          // 7.22 MB
  unsigned short* Bfrag1 = (unsigned short*)(esrc + (size_t)NBKT * ECAP);  // 16 KB
  unsigned short* Bfrag2 = Bfrag1 + 4 * 4 * 64 * 8;           // 6 KB
  int* startg = (int*)(Bfrag2 + 2 * 3 * 64 * 8);              // [N]
  int* cntg   = startg + N_NODES;                             // [N]
  float* norm_src = (float*)(cntg + N_NODES);                 // [N]
  float* norm_dst = norm_src + N_NODES;                       // [N]
  int* gcur  = (int*)(norm_dst + N_NODES);                    // [2*NBKT]
  int* gcur2 = gcur + NBKT;

  k_init<<<16, 256, 0, stream>>>(W1, W2, Bfrag1, Bfrag2, gcur);
  k_part<<<NTILES, 256, 0, stream>>>(src, dst, gcur, gcur2, pairs, spart);
  // merged CSR + out-degree + layer-1 GEMM (independent halves co-run)
  k_mid<<<2 * NBKT + GEMM_BLK, 256, 0, stream>>>(pairs, spart, gcur, gcur2,
                                                 startg, cntg, norm_dst, norm_src, esrc,
                                                 feats, (const uint4*)Bfrag1, t1);
  // layer-1 aggregate + fused layer-2 GEMM (32 nodes/block)
  k_agg1g2<<<N_NODES / 32, 256, 0, stream>>>((const uint4*)t1, startg, cntg, esrc,
                                             norm_dst, norm_src, (const float4*)b1,
                                             (const uint4*)Bfrag2, (float4*)out1, t2);
  // layer-2 aggregate (5 lanes/node)
  k_agg2<<<(N_NODES * 5 + 255) / 256, 256, 0, stream>>>((const uint4*)t2, startg, cntg, esrc,
                                                        norm_dst, b2, (float4*)out2);
}

// Round 12
// 137.828 us; speedup vs baseline: 1.0371x; 1.0371x over previous
//
#include <hip/hip_runtime.h>
#include <hip/hip_bf16.h>

constexpr int N_NODES = 100000;
constexpr int N_EDGES = 1600000;
constexpr int IN_DIM  = 128;
constexpr int HID_DIM = 64;
constexpr int OUT_DIM = 40;

constexpr int BK_SHIFT = 9;                           // 512-node coarse buckets
constexpr int NBKT = (N_NODES + 511) >> 9;            // 196
constexpr int ECAP = 9216;                            // mean 8192, +11 sigma
constexpr int TILE = 4096;
constexpr int EPT  = TILE / 256;                      // 16 edges per thread
constexpr int NTILES = (N_EDGES + TILE - 1) / TILE;   // 391
constexpr int GEMM_BLK = (N_NODES + 63) / 64;         // 1563

typedef __attribute__((ext_vector_type(8))) short short8;
typedef __attribute__((ext_vector_type(4))) float f32x4;

__device__ inline float bf2f(unsigned int u16) {
  union { float f; unsigned int i; } c;
  c.i = u16 << 16;
  return c.f;
}

__device__ inline unsigned short f2bf(float f) {
  union { float f; unsigned int u; } c; c.f = f;
  unsigned int u = c.u + 0x7fffu + ((c.u >> 16) & 1u);
  return (unsigned short)(u >> 16);
}

// Fused partition (+ one trailing block does Bfrag prep).
// Partition: packed (ldst<<17|src) by dst>>9  AND  (src&511) by src>>9.
__global__ __launch_bounds__(256) void k_part(const int* __restrict__ src,
                                              const int* __restrict__ dst,
                                              int* __restrict__ gcur,
                                              int* __restrict__ gcur2,
                                              unsigned int* __restrict__ pairs,
                                              unsigned short* __restrict__ spart,
                                              const float* __restrict__ W1,
                                              const float* __restrict__ W2,
                                              unsigned short* __restrict__ Bfrag1,
                                              unsigned short* __restrict__ Bfrag2) {
  __shared__ int scnt[NBKT], soff[NBKT], gbase[NBKT];
  __shared__ int scnt2[NBKT], soff2[NBKT], gbase2[NBKT];
  __shared__ int sc1[256], sc2[256];
  __shared__ unsigned int sord[TILE];           // 16 KB packed pair
  __shared__ unsigned char sordB[TILE];         // 4 KB bucket id
  __shared__ unsigned short sordS[TILE];        // 8 KB local src idx
  __shared__ unsigned char sordSB[TILE];        // 4 KB bucket id
  int tid = threadIdx.x;

  if (blockIdx.x == NTILES) {
    // ---- Bfrag prep branch (one block) ----
    for (int idx = tid; idx < 4 * 4 * 64 * 8; idx += 256) {
      int j = idx & 7;
      int lane = (idx >> 3) & 63;
      int nt = (idx >> 9) & 3;
      int ks = idx >> 11;
      int k = ks * 32 + 8 * (lane >> 4) + j;
      int col = nt * 16 + (lane & 15);
      Bfrag1[idx] = f2bf(W1[k * HID_DIM + col]);
    }
    for (int idx = tid; idx < 2 * 3 * 64 * 8; idx += 256) {
      int j = idx & 7;
      int lane = (idx >> 3) & 63;
      int nt = (idx >> 9) % 3;
      int ks = idx / (3 * 512);
      int k = ks * 32 + 8 * (lane >> 4) + j;
      int col = nt * 16 + (lane & 15);
      Bfrag2[idx] = (col < OUT_DIM) ? f2bf(W2[k * OUT_DIM + col]) : (unsigned short)0;
    }
    return;
  }

  int tileBase = blockIdx.x * TILE;
  int tcnt = N_EDGES - tileBase; if (tcnt > TILE) tcnt = TILE;
  if (tid < NBKT) { scnt[tid] = 0; scnt2[tid] = 0; }
  __syncthreads();
  int s_[EPT], d_[EPT], pos_[EPT], pos2_[EPT];
#pragma unroll
  for (int t = 0; t < EPT; ++t) {
    int idx = tileBase + t * 256 + tid;
    if (idx < N_EDGES) {
      s_[t] = src[idx];
      d_[t] = dst[idx];
      pos_[t]  = atomicAdd(&scnt[d_[t] >> BK_SHIFT], 1);
      pos2_[t] = atomicAdd(&scnt2[s_[t] >> BK_SHIFT], 1);
    }
  }
  __syncthreads();
  // parallel exclusive scan of both count arrays (NBKT <= 256)
  int v1 = (tid < NBKT) ? scnt[tid] : 0;
  int v2 = (tid < NBKT) ? scnt2[tid] : 0;
  sc1[tid] = v1; sc2[tid] = v2;
  __syncthreads();
  for (int o = 1; o < 256; o <<= 1) {
    int x1 = (tid >= o) ? sc1[tid - o] : 0;
    int x2 = (tid >= o) ? sc2[tid - o] : 0;
    __syncthreads();
    sc1[tid] += x1; sc2[tid] += x2;
    __syncthreads();
  }
  if (tid < NBKT) {
    soff[tid]  = sc1[tid] - v1;
    soff2[tid] = sc2[tid] - v2;
    gbase[tid]  = v1 ? atomicAdd(&gcur[tid],  v1) : 0;
    gbase2[tid] = v2 ? atomicAdd(&gcur2[tid], v2) : 0;
  }
  __syncthreads();
#pragma unroll
  for (int t = 0; t < EPT; ++t) {
    int idx = tileBase + t * 256 + tid;
    if (idx < N_EDGES) {
      int b  = d_[t] >> BK_SHIFT;
      int b2 = s_[t] >> BK_SHIFT;
      int p  = soff[b] + pos_[t];
      int p2 = soff2[b2] + pos2_[t];
      sord[p]  = (unsigned)s_[t] | ((unsigned)(d_[t] & 511) << 17);
      sordB[p] = (unsigned char)b;
      sordS[p2]  = (unsigned short)(s_[t] & 511);
      sordSB[p2] = (unsigned char)b2;
    }
  }
  __syncthreads();
  for (int i = tid; i < tcnt; i += 256) {
    int b = sordB[i];
    int g = gbase[b] + (i - soff[b]);
    if (g < ECAP) pairs[(size_t)b * ECAP + g] = sord[i];
  }
  for (int i = tid; i < tcnt; i += 256) {
    int b = sordSB[i];
    int g = gbase2[b] + (i - soff2[b]);
    if (g < ECAP) spart[(size_t)b * ECAP + g] = sordS[i];
  }
}

// Merged: blocks [0,NBKT) build fine CSR; blocks [NBKT,2*NBKT) build norm_src.
__global__ __launch_bounds__(256) void k_csrdeg(const unsigned int* __restrict__ pairs,
                                                const unsigned short* __restrict__ spart,
                                                const int* __restrict__ gcur,
                                                const int* __restrict__ gcur2,
                                                int* __restrict__ startg,
                                                int* __restrict__ cntg,
                                                float* __restrict__ norm_dst,
                                                float* __restrict__ norm_src,
                                                int* __restrict__ esrc) {
  __shared__ int cnt[512];
  __shared__ int off[512];
  __shared__ int cur[512];
  __shared__ int wsum[256];
  __shared__ int esrcL[ECAP];   // 36 KB
  int tid = threadIdx.x;
  if (blockIdx.x >= NBKT) {
    int b = blockIdx.x - NBKT;
    int node0 = b << BK_SHIFT;
    int nNodes = N_NODES - node0; if (nNodes > 512) nNodes = 512;
    int E = gcur2[b]; if (E > ECAP) E = ECAP;
    cnt[tid] = 0; cnt[tid + 256] = 0;
    __syncthreads();
    const unsigned short* sp = spart + (size_t)b * ECAP;
    for (int i = tid; i < E; i += 256) atomicAdd(&cnt[sp[i]], 1);
    __syncthreads();
    for (int j = tid; j < nNodes; j += 256) {
      int c = cnt[j];
      norm_src[node0 + j] = rsqrtf((float)(c < 1 ? 1 : c));
    }
    return;
  }
  int b = blockIdx.x;
  int node0 = b << BK_SHIFT;
  int nNodes = N_NODES - node0; if (nNodes > 512) nNodes = 512;
  int E = gcur[b]; if (E > ECAP) E = ECAP;
  cnt[tid] = 0; cnt[tid + 256] = 0;
  __syncthreads();
  const unsigned int* pp = pairs + (size_t)b * ECAP;
  for (int i = tid; i < E; i += 256) atomicAdd(&cnt[pp[i] >> 17], 1);
  __syncthreads();
  int v0 = cnt[tid * 2], v1 = cnt[tid * 2 + 1];
  int s = v0 + v1;
  wsum[tid] = s; __syncthreads();
  for (int o = 1; o < 256; o <<= 1) {
    int x = (tid >= o) ? wsum[tid - o] : 0;
    __syncthreads();
    wsum[tid] += x;
    __syncthreads();
  }
  int excl = wsum[tid] - s;
  off[tid * 2] = excl;     cur[tid * 2] = excl;
  off[tid * 2 + 1] = excl + v0; cur[tid * 2 + 1] = excl + v0;
  __syncthreads();
  for (int i = tid; i < E; i += 256) {
    unsigned p = pp[i];
    int pos = atomicAdd(&cur[p >> 17], 1);
    esrcL[pos] = (int)(p & 0x1FFFFu);
  }
  __syncthreads();
  int base = b * ECAP;
  for (int i = tid; i < E; i += 256) esrc[base + i] = esrcL[i];
  for (int j = tid; j < nNodes; j += 256) {
    int c = cnt[j];
    startg[node0 + j] = base + off[j];
    cntg[node0 + j] = c;
    norm_dst[node0 + j] = rsqrtf((float)(c < 1 ? 1 : c));
  }
}

// MFMA GEMM1: t1[row][0..63] = bf16( (feats[row][:] @ W1) * norm_src[row] )
__global__ __launch_bounds__(256) void k_gemm1_mfma(
    const float* __restrict__ feats, const uint4* __restrict__ Bfrag1,
    const float* __restrict__ norm_src, __hip_bfloat16* __restrict__ t1) {
  int tid = threadIdx.x;
  int w = tid >> 6, lane = tid & 63;
  int row0 = blockIdx.x * 64 + w * 16;
  int arow = row0 + (lane & 15);
  int arowc = arow < N_NODES ? arow : N_NODES - 1;
  int half = lane >> 4;

  const float4* fr = (const float4*)(feats + (size_t)arowc * IN_DIM);
  f32x4 acc[4] = {{0.f,0.f,0.f,0.f},{0.f,0.f,0.f,0.f},{0.f,0.f,0.f,0.f},{0.f,0.f,0.f,0.f}};
#pragma unroll
  for (int ks = 0; ks < 4; ++ks) {
    float4 p0 = fr[ks * 8 + 2 * half];
    float4 p1 = fr[ks * 8 + 2 * half + 1];
    short8 a;
    a[0] = (short)f2bf(p0.x); a[1] = (short)f2bf(p0.y);
    a[2] = (short)f2bf(p0.z); a[3] = (short)f2bf(p0.w);
    a[4] = (short)f2bf(p1.x); a[5] = (short)f2bf(p1.y);
    a[6] = (short)f2bf(p1.z); a[7] = (short)f2bf(p1.w);
#pragma unroll
    for (int nt = 0; nt < 4; ++nt) {
      uint4 bu = Bfrag1[(ks * 4 + nt) * 64 + lane];
      short8 b = *(const short8*)&bu;
      acc[nt] = __builtin_amdgcn_mfma_f32_16x16x32_bf16(a, b, acc[nt], 0, 0, 0);
    }
  }
  int col = lane & 15;
  int rbase = row0 + half * 4;
#pragma unroll
  for (int r = 0; r < 4; ++r) {
    int grow = rbase + r;
    if (grow < N_NODES) {
      float ns = norm_src[grow];
#pragma unroll
      for (int nt = 0; nt < 4; ++nt) {
        unsigned short h = f2bf(acc[nt][r] * ns);
        *((unsigned short*)t1 + (size_t)grow * HID_DIM + nt * 16 + col) = h;
      }
    }
  }
}

// Fused layer-1 gather + layer-2 GEMM.
// 32 nodes/block, 8 lanes per node, uint4 per lane; 16-deep masked MLP batches.
__global__ __launch_bounds__(256) void k_agg1g2(
    const uint4* __restrict__ t1, const int* __restrict__ startg,
    const int* __restrict__ cntg, const int* __restrict__ esrc,
    const float* __restrict__ norm_dst, const float* __restrict__ norm_src,
    const float4* __restrict__ b1v, const uint4* __restrict__ Bfrag2,
    float4* __restrict__ out1, __hip_bfloat16* __restrict__ t2) {
  __shared__ unsigned short h1s[32][64];   // 4 KB bf16 A-tile
  int tid = threadIdx.x;
  int g = tid >> 3, q = tid & 7;
  int n = blockIdx.x * 32 + g;          // 100000 = 3125*32 exact
  int s0 = startg[n];
  int c  = cntg[n];
  const int* bk = esrc + s0;
  float a0 = 0.f, a1 = 0.f, a2 = 0.f, a3 = 0.f;
  float a4 = 0.f, a5 = 0.f, a6 = 0.f, a7 = 0.f;
  for (int i = 0; i < c; i += 16) {
#pragma unroll
    for (int t = 0; t < 16; ++t) {
      int ii = i + t;
      bool ok = ii < c;
      int s = bk[ok ? ii : 0];
      uint4 v = t1[(size_t)s * 8 + q];
      unsigned vx = ok ? v.x : 0u;
      unsigned vy = ok ? v.y : 0u;
      unsigned vz = ok ? v.z : 0u;
      unsigned vw = ok ? v.w : 0u;
      a0 += bf2f(vx & 0xffffu); a1 += bf2f(vx >> 16);
      a2 += bf2f(vy & 0xffffu); a3 += bf2f(vy >> 16);
      a4 += bf2f(vz & 0xffffu); a5 += bf2f(vz >> 16);
      a6 += bf2f(vw & 0xffffu); a7 += bf2f(vw >> 16);
    }
  }
  float nd = norm_dst[n];
  float4 bb0 = b1v[q * 2];
  float4 bb1 = b1v[q * 2 + 1];
  float h0 = fmaxf(a0 * nd + bb0.x, 0.f);
  float h1 = fmaxf(a1 * nd + bb0.y, 0.f);
  float h2 = fmaxf(a2 * nd + bb0.z, 0.f);
  float h3 = fmaxf(a3 * nd + bb0.w, 0.f);
  float h4 = fmaxf(a4 * nd + bb1.x, 0.f);
  float h5 = fmaxf(a5 * nd + bb1.y, 0.f);
  float h6 = fmaxf(a6 * nd + bb1.z, 0.f);
  float h7 = fmaxf(a7 * nd + bb1.w, 0.f);
  out1[(size_t)n * 16 + q * 2]     = make_float4(h0, h1, h2, h3);
  out1[(size_t)n * 16 + q * 2 + 1] = make_float4(h4, h5, h6, h7);
  float ns = norm_src[n];
  uint4 pk;
  pk.x = (unsigned)f2bf(h0 * ns) | ((unsigned)f2bf(h1 * ns) << 16);
  pk.y = (unsigned)f2bf(h2 * ns) | ((unsigned)f2bf(h3 * ns) << 16);
  pk.z = (unsigned)f2bf(h4 * ns) | ((unsigned)f2bf(h5 * ns) << 16);
  pk.w = (unsigned)f2bf(h6 * ns) | ((unsigned)f2bf(h7 * ns) << 16);
  *(uint4*)&h1s[g][q * 8] = pk;
  __syncthreads();
  if (tid < 128) {
    int wave = tid >> 6;
    int lane = tid & 63;
    int r = lane & 15, half = lane >> 4;
    int row = wave * 16 + r;
    f32x4 acc[3] = {{0.f,0.f,0.f,0.f},{0.f,0.f,0.f,0.f},{0.f,0.f,0.f,0.f}};
#pragma unroll
    for (int ks = 0; ks < 2; ++ks) {
      short8 a = *(const short8*)&h1s[row][ks * 32 + 8 * half];
#pragma unroll
      for (int nt = 0; nt < 3; ++nt) {
        uint4 bu = Bfrag2[(ks * 3 + nt) * 64 + lane];
        short8 b = *(const short8*)&bu;
        acc[nt] = __builtin_amdgcn_mfma_f32_16x16x32_bf16(a, b, acc[nt], 0, 0, 0);
      }
    }
    int col = lane & 15;
#pragma unroll
    for (int r2 = 0; r2 < 4; ++r2) {
      int node = blockIdx.x * 32 + wave * 16 + half * 4 + r2;
#pragma unroll
      for (int nt = 0; nt < 3; ++nt) {
        int j = nt * 16 + col;
        if (j < OUT_DIM)
          *((unsigned short*)t2 + (size_t)node * OUT_DIM + j) = f2bf(acc[nt][r2]);
      }
    }
  }
}

// Layer-2 gather: 5 lanes per node, uint4 per lane; 16-deep masked MLP batches.
__global__ __launch_bounds__(256) void k_agg2(
    const uint4* __restrict__ t2, const int* __restrict__ startg,
    const int* __restrict__ cntg, const int* __restrict__ esrc,
    const float* __restrict__ norm_dst, const float* __restrict__ b2,
    float4* __restrict__ out2) {
  int idx = blockIdx.x * blockDim.x + threadIdx.x;
  int n = idx / 5;
  int q = idx - n * 5;
  if (n >= N_NODES) return;
  int s0 = startg[n];
  int c  = cntg[n];
  const int* bk = esrc + s0;
  float a0 = 0.f, a1 = 0.f, a2 = 0.f, a3 = 0.f;
  float a4 = 0.f, a5 = 0.f, a6 = 0.f, a7 = 0.f;
  for (int i = 0; i < c; i += 16) {
#pragma unroll
    for (int t = 0; t < 16; ++t) {
      int ii = i + t;
      bool ok = ii < c;
      int s = bk[ok ? ii : 0];
      uint4 v = t2[(size_t)s * 5 + q];
      unsigned vx = ok ? v.x : 0u;
      unsigned vy = ok ? v.y : 0u;
      unsigned vz = ok ? v.z : 0u;
      unsigned vw = ok ? v.w : 0u;
      a0 += bf2f(vx & 0xffffu); a1 += bf2f(vx >> 16);
      a2 += bf2f(vy & 0xffffu); a3 += bf2f(vy >> 16);
      a4 += bf2f(vz & 0xffffu); a5 += bf2f(vz >> 16);
      a6 += bf2f(vw & 0xffffu); a7 += bf2f(vw >> 16);
    }
  }
  float nd = norm_dst[n];
  float4 bb0 = *(const float4*)(b2 + q * 8);
  float4 bb1 = *(const float4*)(b2 + q * 8 + 4);
  out2[(size_t)n * 10 + q * 2] =
      make_float4(a0 * nd + bb0.x, a1 * nd + bb0.y, a2 * nd + bb0.z, a3 * nd + bb0.w);
  out2[(size_t)n * 10 + q * 2 + 1] =
      make_float4(a4 * nd + bb1.x, a5 * nd + bb1.y, a6 * nd + bb1.z, a7 * nd + bb1.w);
}

extern "C" void kernel_launch(void* const* d_in, const int* in_sizes, int n_in,
                              void* d_out, int out_size, void* d_ws, size_t ws_size,
                              hipStream_t stream) {
  const float* feats = (const float*)d_in[0];
  const float* W1    = (const float*)d_in[1];
  const float* b1    = (const float*)d_in[2];
  const float* W2    = (const float*)d_in[3];
  const float* b2    = (const float*)d_in[4];
  const int*   src   = (const int*)d_in[5];
  const int*   dst   = (const int*)d_in[6];

  float* out  = (float*)d_out;
  float* out1 = out;                                  // [N, 64]
  float* out2 = out + (size_t)N_NODES * HID_DIM;      // [N, 40]

  __hip_bfloat16* t1 = (__hip_bfloat16*)d_ws;                 // 12.8 MB
  __hip_bfloat16* t2 = t1 + (size_t)N_NODES * HID_DIM;        //  8.0 MB
  unsigned int* pairs = (unsigned int*)(t2 + (size_t)N_NODES * OUT_DIM);   // 7.22 MB
  unsigned short* spart = (unsigned short*)(pairs + (size_t)NBKT * ECAP);  // 3.61 MB
  int* esrc   = (int*)(spart + (size_t)NBKT * ECAP);          // 7.22 MB
  unsigned short* Bfrag1 = (unsigned short*)(esrc + (size_t)NBKT * ECAP);  // 16 KB
  unsigned short* Bfrag2 = Bfrag1 + 4 * 4 * 64 * 8;           // 6 KB
  int* startg = (int*)(Bfrag2 + 2 * 3 * 64 * 8);              // [N]
  int* cntg   = startg + N_NODES;                             // [N]
  float* norm_src = (float*)(cntg + N_NODES);                 // [N]
  float* norm_dst = norm_src + N_NODES;                       // [N]
  int* gcur  = (int*)(norm_dst + N_NODES);                    // [2*NBKT]
  int* gcur2 = gcur + NBKT;

  hipMemsetAsync(gcur, 0, 2 * NBKT * sizeof(int), stream);
  k_part<<<NTILES + 1, 256, 0, stream>>>(src, dst, gcur, gcur2, pairs, spart,
                                         W1, W2, Bfrag1, Bfrag2);
  k_csrdeg<<<2 * NBKT, 256, 0, stream>>>(pairs, spart, gcur, gcur2,
                                         startg, cntg, norm_dst, norm_src, esrc);

  // layer 1 GEMM
  k_gemm1_mfma<<<GEMM_BLK, 256, 0, stream>>>(feats, (const uint4*)Bfrag1, norm_src, t1);
  // layer-1 aggregate + fused layer-2 GEMM (32 nodes/block)
  k_agg1g2<<<N_NODES / 32, 256, 0, stream>>>((const uint4*)t1, startg, cntg, esrc,
                                             norm_dst, norm_src, (const float4*)b1,
                                             (const uint4*)Bfrag2, (float4*)out1, t2);
  // layer-2 aggregate (5 lanes/node)
  k_agg2<<<(N_NODES * 5 + 255) / 256, 256, 0, stream>>>((const uint4*)t2, startg, cntg, esrc,
                                                        norm_dst, b2, (float4*)out2);
}

// Round 13
// 136.823 us; speedup vs baseline: 1.0447x; 1.0073x over previous
//
#include <hip/hip_runtime.h>
#include <hip/hip_bf16.h>

constexpr int N_NODES = 100000;
constexpr int N_EDGES = 1600000;
constexpr int IN_DIM  = 128;
constexpr int HID_DIM = 64;
constexpr int OUT_DIM = 40;

constexpr int BK_SHIFT = 9;                           // 512-node coarse buckets
constexpr int NBKT = (N_NODES + 511) >> 9;            // 196
constexpr int ECAP = 9216;                            // mean 8192, +11 sigma
constexpr int TILE = 4096;
constexpr int EPT  = TILE / 256;                      // 16 edges per thread
constexpr int NTILES = (N_EDGES + TILE - 1) / TILE;   // 391
constexpr int GEMM_BLK = (N_NODES + 63) / 64;         // 1563

typedef __attribute__((ext_vector_type(8))) short short8;
typedef __attribute__((ext_vector_type(4))) float f32x4;

__device__ inline float bf2f(unsigned int u16) {
  union { float f; unsigned int i; } c;
  c.i = u16 << 16;
  return c.f;
}

__device__ inline unsigned short f2bf(float f) {
  union { float f; unsigned int u; } c; c.f = f;
  unsigned int u = c.u + 0x7fffu + ((c.u >> 16) & 1u);
  return (unsigned short)(u >> 16);
}

// Fused partition (+ one trailing block does Bfrag prep).
// Partition: packed (ldst<<17|src) by dst>>9  AND  (src&511) by src>>9.
__global__ __launch_bounds__(256) void k_part(const int* __restrict__ src,
                                              const int* __restrict__ dst,
                                              int* __restrict__ gcur,
                                              int* __restrict__ gcur2,
                                              unsigned int* __restrict__ pairs,
                                              unsigned short* __restrict__ spart,
                                              const float* __restrict__ W1,
                                              const float* __restrict__ W2,
                                              unsigned short* __restrict__ Bfrag1,
                                              unsigned short* __restrict__ Bfrag2) {
  __shared__ int scnt[NBKT], soff[NBKT], gbase[NBKT];
  __shared__ int scnt2[NBKT], soff2[NBKT], gbase2[NBKT];
  __shared__ int sc1[256], sc2[256];
  __shared__ unsigned int sord[TILE];           // 16 KB packed pair
  __shared__ unsigned char sordB[TILE];         // 4 KB bucket id
  __shared__ unsigned short sordS[TILE];        // 8 KB local src idx
  __shared__ unsigned char sordSB[TILE];        // 4 KB bucket id
  int tid = threadIdx.x;

  if (blockIdx.x == NTILES) {
    // ---- Bfrag prep branch (one block) ----
    for (int idx = tid; idx < 4 * 4 * 64 * 8; idx += 256) {
      int j = idx & 7;
      int lane = (idx >> 3) & 63;
      int nt = (idx >> 9) & 3;
      int ks = idx >> 11;
      int k = ks * 32 + 8 * (lane >> 4) + j;
      int col = nt * 16 + (lane & 15);
      Bfrag1[idx] = f2bf(W1[k * HID_DIM + col]);
    }
    for (int idx = tid; idx < 2 * 3 * 64 * 8; idx += 256) {
      int j = idx & 7;
      int lane = (idx >> 3) & 63;
      int nt = (idx >> 9) % 3;
      int ks = idx / (3 * 512);
      int k = ks * 32 + 8 * (lane >> 4) + j;
      int col = nt * 16 + (lane & 15);
      Bfrag2[idx] = (col < OUT_DIM) ? f2bf(W2[k * OUT_DIM + col]) : (unsigned short)0;
    }
    return;
  }

  int tileBase = blockIdx.x * TILE;
  int tcnt = N_EDGES - tileBase; if (tcnt > TILE) tcnt = TILE;
  if (tid < NBKT) { scnt[tid] = 0; scnt2[tid] = 0; }
  __syncthreads();
  int s_[EPT], d_[EPT], pos_[EPT], pos2_[EPT];
#pragma unroll
  for (int t = 0; t < EPT; ++t) {
    int idx = tileBase + t * 256 + tid;
    if (idx < N_EDGES) {
      s_[t] = src[idx];
      d_[t] = dst[idx];
      pos_[t]  = atomicAdd(&scnt[d_[t] >> BK_SHIFT], 1);
      pos2_[t] = atomicAdd(&scnt2[s_[t] >> BK_SHIFT], 1);
    }
  }
  __syncthreads();
  // parallel exclusive scan of both count arrays (NBKT <= 256)
  int v1 = (tid < NBKT) ? scnt[tid] : 0;
  int v2 = (tid < NBKT) ? scnt2[tid] : 0;
  sc1[tid] = v1; sc2[tid] = v2;
  __syncthreads();
  for (int o = 1; o < 256; o <<= 1) {
    int x1 = (tid >= o) ? sc1[tid - o] : 0;
    int x2 = (tid >= o) ? sc2[tid - o] : 0;
    __syncthreads();
    sc1[tid] += x1; sc2[tid] += x2;
    __syncthreads();
  }
  if (tid < NBKT) {
    soff[tid]  = sc1[tid] - v1;
    soff2[tid] = sc2[tid] - v2;
    gbase[tid]  = v1 ? atomicAdd(&gcur[tid],  v1) : 0;
    gbase2[tid] = v2 ? atomicAdd(&gcur2[tid], v2) : 0;
  }
  __syncthreads();
#pragma unroll
  for (int t = 0; t < EPT; ++t) {
    int idx = tileBase + t * 256 + tid;
    if (idx < N_EDGES) {
      int b  = d_[t] >> BK_SHIFT;
      int b2 = s_[t] >> BK_SHIFT;
      int p  = soff[b] + pos_[t];
      int p2 = soff2[b2] + pos2_[t];
      sord[p]  = (unsigned)s_[t] | ((unsigned)(d_[t] & 511) << 17);
      sordB[p] = (unsigned char)b;
      sordS[p2]  = (unsigned short)(s_[t] & 511);
      sordSB[p2] = (unsigned char)b2;
    }
  }
  __syncthreads();
  for (int i = tid; i < tcnt; i += 256) {
    int b = sordB[i];
    int g = gbase[b] + (i - soff[b]);
    if (g < ECAP) pairs[(size_t)b * ECAP + g] = sord[i];
  }
  for (int i = tid; i < tcnt; i += 256) {
    int b = sordSB[i];
    int g = gbase2[b] + (i - soff2[b]);
    if (g < ECAP) spart[(size_t)b * ECAP + g] = sordS[i];
  }
}

// Out-degree histogram -> norm_src (196 blocks; runs before the fused kernel).
__global__ __launch_bounds__(256) void k_degsrc(const unsigned short* __restrict__ spart,
                                                const int* __restrict__ gcur2,
                                                float* __restrict__ norm_src) {
  __shared__ int cnt[512];
  int b = blockIdx.x, tid = threadIdx.x;
  int node0 = b << BK_SHIFT;
  int nNodes = N_NODES - node0; if (nNodes > 512) nNodes = 512;
  int E = gcur2[b]; if (E > ECAP) E = ECAP;
  cnt[tid] = 0; cnt[tid + 256] = 0;
  __syncthreads();
  const unsigned short* sp = spart + (size_t)b * ECAP;
  for (int i = tid; i < E; i += 256) atomicAdd(&cnt[sp[i]], 1);
  __syncthreads();
  for (int j = tid; j < nNodes; j += 256) {
    int c = cnt[j];
    norm_src[node0 + j] = rsqrtf((float)(c < 1 ? 1 : c));
  }
}

// Fused: blocks [0,NBKT) build the fine CSR; blocks [NBKT,NBKT+GEMM_BLK) run
// GEMM1 (t1 = bf16((feats@W1) * norm_src)). The two branches share no data.
__global__ __launch_bounds__(256) void k_csr_gemm1(
    const unsigned int* __restrict__ pairs, const int* __restrict__ gcur,
    int* __restrict__ startg, int* __restrict__ cntg,
    float* __restrict__ norm_dst, int* __restrict__ esrc,
    const float* __restrict__ feats, const uint4* __restrict__ Bfrag1,
    const float* __restrict__ norm_src, __hip_bfloat16* __restrict__ t1) {
  __shared__ int cnt[512];
  __shared__ int off[512];
  __shared__ int cur[512];
  __shared__ int wsum[256];
  __shared__ int esrcL[ECAP];   // 36 KB
  int tid = threadIdx.x;
  int bx = blockIdx.x;

  if (bx >= NBKT) {
    // ---- GEMM1 branch ----
    int blk = bx - NBKT;
    int w = tid >> 6, lane = tid & 63;
    int row0 = blk * 64 + w * 16;
    int arow = row0 + (lane & 15);
    int arowc = arow < N_NODES ? arow : N_NODES - 1;
    int half = lane >> 4;
    const float4* fr = (const float4*)(feats + (size_t)arowc * IN_DIM);
    f32x4 acc[4] = {{0.f,0.f,0.f,0.f},{0.f,0.f,0.f,0.f},{0.f,0.f,0.f,0.f},{0.f,0.f,0.f,0.f}};
#pragma unroll
    for (int ks = 0; ks < 4; ++ks) {
      float4 p0 = fr[ks * 8 + 2 * half];
      float4 p1 = fr[ks * 8 + 2 * half + 1];
      short8 a;
      a[0] = (short)f2bf(p0.x); a[1] = (short)f2bf(p0.y);
      a[2] = (short)f2bf(p0.z); a[3] = (short)f2bf(p0.w);
      a[4] = (short)f2bf(p1.x); a[5] = (short)f2bf(p1.y);
      a[6] = (short)f2bf(p1.z); a[7] = (short)f2bf(p1.w);
#pragma unroll
      for (int nt = 0; nt < 4; ++nt) {
        uint4 bu = Bfrag1[(ks * 4 + nt) * 64 + lane];
        short8 b = *(const short8*)&bu;
        acc[nt] = __builtin_amdgcn_mfma_f32_16x16x32_bf16(a, b, acc[nt], 0, 0, 0);
      }
    }
    int col = lane & 15;
    int rbase = row0 + half * 4;
#pragma unroll
    for (int r = 0; r < 4; ++r) {
      int grow = rbase + r;
      if (grow < N_NODES) {
        float ns = norm_src[grow];
#pragma unroll
        for (int nt = 0; nt < 4; ++nt) {
          unsigned short h = f2bf(acc[nt][r] * ns);
          *((unsigned short*)t1 + (size_t)grow * HID_DIM + nt * 16 + col) = h;
        }
      }
    }
    return;
  }

  // ---- fine CSR branch ----
  int b = bx;
  int node0 = b << BK_SHIFT;
  int nNodes = N_NODES - node0; if (nNodes > 512) nNodes = 512;
  int E = gcur[b]; if (E > ECAP) E = ECAP;
  cnt[tid] = 0; cnt[tid + 256] = 0;
  __syncthreads();
  const unsigned int* pp = pairs + (size_t)b * ECAP;
  for (int i = tid; i < E; i += 256) atomicAdd(&cnt[pp[i] >> 17], 1);
  __syncthreads();
  int v0 = cnt[tid * 2], v1 = cnt[tid * 2 + 1];
  int s = v0 + v1;
  wsum[tid] = s; __syncthreads();
  for (int o = 1; o < 256; o <<= 1) {
    int x = (tid >= o) ? wsum[tid - o] : 0;
    __syncthreads();
    wsum[tid] += x;
    __syncthreads();
  }
  int excl = wsum[tid] - s;
  off[tid * 2] = excl;     cur[tid * 2] = excl;
  off[tid * 2 + 1] = excl + v0; cur[tid * 2 + 1] = excl + v0;
  __syncthreads();
  for (int i = tid; i < E; i += 256) {
    unsigned p = pp[i];
    int pos = atomicAdd(&cur[p >> 17], 1);
    esrcL[pos] = (int)(p & 0x1FFFFu);
  }
  __syncthreads();
  int base = b * ECAP;
  for (int i = tid; i < E; i += 256) esrc[base + i] = esrcL[i];
  for (int j = tid; j < nNodes; j += 256) {
    int c = cnt[j];
    startg[node0 + j] = base + off[j];
    cntg[node0 + j] = c;
    norm_dst[node0 + j] = rsqrtf((float)(c < 1 ? 1 : c));
  }
}

// Fused layer-1 gather + layer-2 GEMM.
// 32 nodes/block, 8 lanes per node, uint4 per lane; 8-deep masked MLP batches.
__global__ __launch_bounds__(256) void k_agg1g2(
    const uint4* __restrict__ t1, const int* __restrict__ startg,
    const int* __restrict__ cntg, const int* __restrict__ esrc,
    const float* __restrict__ norm_dst, const float* __restrict__ norm_src,
    const float4* __restrict__ b1v, const uint4* __restrict__ Bfrag2,
    float4* __restrict__ out1, __hip_bfloat16* __restrict__ t2) {
  __shared__ unsigned short h1s[32][64];   // 4 KB bf16 A-tile
  int tid = threadIdx.x;
  int g = tid >> 3, q = tid & 7;
  int n = blockIdx.x * 32 + g;          // 100000 = 3125*32 exact
  int s0 = startg[n];
  int c  = cntg[n];
  const int* bk = esrc + s0;
  float a0 = 0.f, a1 = 0.f, a2 = 0.f, a3 = 0.f;
  float a4 = 0.f, a5 = 0.f, a6 = 0.f, a7 = 0.f;
  for (int i = 0; i < c; i += 8) {
#pragma unroll
    for (int t = 0; t < 8; ++t) {
      int ii = i + t;
      bool ok = ii < c;
      int s = bk[ok ? ii : 0];
      uint4 v = t1[(size_t)s * 8 + q];
      unsigned vx = ok ? v.x : 0u;
      unsigned vy = ok ? v.y : 0u;
      unsigned vz = ok ? v.z : 0u;
      unsigned vw = ok ? v.w : 0u;
      a0 += bf2f(vx & 0xffffu); a1 += bf2f(vx >> 16);
      a2 += bf2f(vy & 0xffffu); a3 += bf2f(vy >> 16);
      a4 += bf2f(vz & 0xffffu); a5 += bf2f(vz >> 16);
      a6 += bf2f(vw & 0xffffu); a7 += bf2f(vw >> 16);
    }
  }
  float nd = norm_dst[n];
  float4 bb0 = b1v[q * 2];
  float4 bb1 = b1v[q * 2 + 1];
  float h0 = fmaxf(a0 * nd + bb0.x, 0.f);
  float h1 = fmaxf(a1 * nd + bb0.y, 0.f);
  float h2 = fmaxf(a2 * nd + bb0.z, 0.f);
  float h3 = fmaxf(a3 * nd + bb0.w, 0.f);
  float h4 = fmaxf(a4 * nd + bb1.x, 0.f);
  float h5 = fmaxf(a5 * nd + bb1.y, 0.f);
  float h6 = fmaxf(a6 * nd + bb1.z, 0.f);
  float h7 = fmaxf(a7 * nd + bb1.w, 0.f);
  out1[(size_t)n * 16 + q * 2]     = make_float4(h0, h1, h2, h3);
  out1[(size_t)n * 16 + q * 2 + 1] = make_float4(h4, h5, h6, h7);
  float ns = norm_src[n];
  uint4 pk;
  pk.x = (unsigned)f2bf(h0 * ns) | ((unsigned)f2bf(h1 * ns) << 16);
  pk.y = (unsigned)f2bf(h2 * ns) | ((unsigned)f2bf(h3 * ns) << 16);
  pk.z = (unsigned)f2bf(h4 * ns) | ((unsigned)f2bf(h5 * ns) << 16);
  pk.w = (unsigned)f2bf(h6 * ns) | ((unsigned)f2bf(h7 * ns) << 16);
  *(uint4*)&h1s[g][q * 8] = pk;
  __syncthreads();
  if (tid < 128) {
    int wave = tid >> 6;
    int lane = tid & 63;
    int r = lane & 15, half = lane >> 4;
    int row = wave * 16 + r;
    f32x4 acc[3] = {{0.f,0.f,0.f,0.f},{0.f,0.f,0.f,0.f},{0.f,0.f,0.f,0.f}};
#pragma unroll
    for (int ks = 0; ks < 2; ++ks) {
      short8 a = *(const short8*)&h1s[row][ks * 32 + 8 * half];
#pragma unroll
      for (int nt = 0; nt < 3; ++nt) {
        uint4 bu = Bfrag2[(ks * 3 + nt) * 64 + lane];
        short8 b = *(const short8*)&bu;
        acc[nt] = __builtin_amdgcn_mfma_f32_16x16x32_bf16(a, b, acc[nt], 0, 0, 0);
      }
    }
    int col = lane & 15;
#pragma unroll
    for (int r2 = 0; r2 < 4; ++r2) {
      int node = blockIdx.x * 32 + wave * 16 + half * 4 + r2;
#pragma unroll
      for (int nt = 0; nt < 3; ++nt) {
        int j = nt * 16 + col;
        if (j < OUT_DIM)
          *((unsigned short*)t2 + (size_t)node * OUT_DIM + j) = f2bf(acc[nt][r2]);
      }
    }
  }
}

// Layer-2 gather: 5 lanes per node, uint4 per lane; 8-deep masked MLP batches.
__global__ __launch_bounds__(256) void k_agg2(
    const uint4* __restrict__ t2, const int* __restrict__ startg,
    const int* __restrict__ cntg, const int* __restrict__ esrc,
    const float* __restrict__ norm_dst, const float* __restrict__ b2,
    float4* __restrict__ out2) {
  int idx = blockIdx.x * blockDim.x + threadIdx.x;
  int n = idx / 5;
  int q = idx - n * 5;
  if (n >= N_NODES) return;
  int s0 = startg[n];
  int c  = cntg[n];
  const int* bk = esrc + s0;
  float a0 = 0.f, a1 = 0.f, a2 = 0.f, a3 = 0.f;
  float a4 = 0.f, a5 = 0.f, a6 = 0.f, a7 = 0.f;
  for (int i = 0; i < c; i += 8) {
#pragma unroll
    for (int t = 0; t < 8; ++t) {
      int ii = i + t;
      bool ok = ii < c;
      int s = bk[ok ? ii : 0];
      uint4 v = t2[(size_t)s * 5 + q];
      unsigned vx = ok ? v.x : 0u;
      unsigned vy = ok ? v.y : 0u;
      unsigned vz = ok ? v.z : 0u;
      unsigned vw = ok ? v.w : 0u;
      a0 += bf2f(vx & 0xffffu); a1 += bf2f(vx >> 16);
      a2 += bf2f(vy & 0xffffu); a3 += bf2f(vy >> 16);
      a4 += bf2f(vz & 0xffffu); a5 += bf2f(vz >> 16);
      a6 += bf2f(vw & 0xffffu); a7 += bf2f(vw >> 16);
    }
  }
  float nd = norm_dst[n];
  float4 bb0 = *(const float4*)(b2 + q * 8);
  float4 bb1 = *(const float4*)(b2 + q * 8 + 4);
  out2[(size_t)n * 10 + q * 2] =
      make_float4(a0 * nd + bb0.x, a1 * nd + bb0.y, a2 * nd + bb0.z, a3 * nd + bb0.w);
  out2[(size_t)n * 10 + q * 2 + 1] =
      make_float4(a4 * nd + bb1.x, a5 * nd + bb1.y, a6 * nd + bb1.z, a7 * nd + bb1.w);
}

extern "C" void kernel_launch(void* const* d_in, const int* in_sizes, int n_in,
                              void* d_out, int out_size, void* d_ws, size_t ws_size,
                              hipStream_t stream) {
  const float* feats = (const float*)d_in[0];
  const float* W1    = (const float*)d_in[1];
  const float* b1    = (const float*)d_in[2];
  const float* W2    = (const float*)d_in[3];
  const float* b2    = (const float*)d_in[4];
  const int*   src   = (const int*)d_in[5];
  const int*   dst   = (const int*)d_in[6];

  float* out  = (float*)d_out;
  float* out1 = out;                                  // [N, 64]
  float* out2 = out + (size_t)N_NODES * HID_DIM;      // [N, 40]

  __hip_bfloat16* t1 = (__hip_bfloat16*)d_ws;                 // 12.8 MB
  __hip_bfloat16* t2 = t1 + (size_t)N_NODES * HID_DIM;        //  8.0 MB
  unsigned int* pairs = (unsigned int*)(t2 + (size_t)N_NODES * OUT_DIM);   // 7.22 MB
  unsigned short* spart = (unsigned short*)(pairs + (size_t)NBKT * ECAP);  // 3.61 MB
  int* esrc   = (int*)(spart + (size_t)NBKT * ECAP);          // 7.22 MB
  unsigned short* Bfrag1 = (unsigned short*)(esrc + (size_t)NBKT * ECAP);  // 16 KB
  unsigned short* Bfrag2 = Bfrag1 + 4 * 4 * 64 * 8;           // 6 KB
  int* startg = (int*)(Bfrag2 + 2 * 3 * 64 * 8);              // [N]
  int* cntg   = startg + N_NODES;                             // [N]
  float* norm_src = (float*)(cntg + N_NODES);                 // [N]
  float* norm_dst = norm_src + N_NODES;                       // [N]
  int* gcur  = (int*)(norm_dst + N_NODES);                    // [2*NBKT]
  int* gcur2 = gcur + NBKT;

  hipMemsetAsync(gcur, 0, 2 * NBKT * sizeof(int), stream);
  k_part<<<NTILES + 1, 256, 0, stream>>>(src, dst, gcur, gcur2, pairs, spart,
                                         W1, W2, Bfrag1, Bfrag2);
  // out-degree -> norm_src (needed by the fused kernel's gemm1 branch)
  k_degsrc<<<NBKT, 256, 0, stream>>>(spart, gcur2, norm_src);
  // fused CSR build + layer-1 GEMM (branches are independent; co-run)
  k_csr_gemm1<<<NBKT + GEMM_BLK, 256, 0, stream>>>(pairs, gcur, startg, cntg,
                                                   norm_dst, esrc,
                                                   feats, (const uint4*)Bfrag1,
                                                   norm_src, t1);
  // layer-1 aggregate + fused layer-2 GEMM (32 nodes/block)
  k_agg1g2<<<N_NODES / 32, 256, 0, stream>>>((const uint4*)t1, startg, cntg, esrc,
                                             norm_dst, norm_src, (const float4*)b1,
                                             (const uint4*)Bfrag2, (float4*)out1, t2);
  // layer-2 aggregate (5 lanes/node)
  k_agg2<<<(N_NODES * 5 + 255) / 256, 256, 0, stream>>>((const uint4*)t2, startg, cntg, esrc,
                                                        norm_dst, b2, (float4*)out2);
}

// Round 14
// 134.123 us; speedup vs baseline: 1.0657x; 1.0201x over previous
//
#include <hip/hip_runtime.h>
#include <hip/hip_bf16.h>

constexpr int N_NODES = 100000;
constexpr int N_EDGES = 1600000;
constexpr int IN_DIM  = 128;
constexpr int HID_DIM = 64;
constexpr int OUT_DIM = 40;

constexpr int BK_SHIFT = 9;                           // 512-node coarse buckets
constexpr int NBKT = (N_NODES + 511) >> 9;            // 196
constexpr int ECAP = 9216;                            // mean 8192, +11 sigma
constexpr int TILE = 4096;
constexpr int EPT  = TILE / 256;                      // 16 edges per thread
constexpr int NTILES = (N_EDGES + TILE - 1) / TILE;   // 391
constexpr int GEMM_BLK = (N_NODES + 63) / 64;         // 1563

typedef __attribute__((ext_vector_type(8))) short short8;
typedef __attribute__((ext_vector_type(4))) float f32x4;

__device__ inline float bf2f(unsigned int u16) {
  union { float f; unsigned int i; } c;
  c.i = u16 << 16;
  return c.f;
}

__device__ inline unsigned short f2bf(float f) {
  union { float f; unsigned int u; } c; c.f = f;
  unsigned int u = c.u + 0x7fffu + ((c.u >> 16) & 1u);
  return (unsigned short)(u >> 16);
}

// init: zero bucket cursors + build W1/W2 MFMA B-fragments (bf16). Grid-strided.
__global__ void k_init(const float* __restrict__ W1, const float* __restrict__ W2,
                       unsigned short* __restrict__ Bfrag1, unsigned short* __restrict__ Bfrag2,
                       int* __restrict__ gcur) {
  int tid = blockIdx.x * blockDim.x + threadIdx.x;
  int stride = gridDim.x * blockDim.x;
  for (int i = tid; i < 2 * NBKT; i += stride) gcur[i] = 0;
  for (int idx = tid; idx < 4 * 4 * 64 * 8; idx += stride) {
    int j = idx & 7;
    int lane = (idx >> 3) & 63;
    int nt = (idx >> 9) & 3;
    int ks = idx >> 11;
    int k = ks * 32 + 8 * (lane >> 4) + j;
    int col = nt * 16 + (lane & 15);
    Bfrag1[idx] = f2bf(W1[k * HID_DIM + col]);
  }
  for (int idx = tid; idx < 2 * 3 * 64 * 8; idx += stride) {
    int j = idx & 7;
    int lane = (idx >> 3) & 63;
    int nt = (idx >> 9) % 3;
    int ks = idx / (3 * 512);
    int k = ks * 32 + 8 * (lane >> 4) + j;
    int col = nt * 16 + (lane & 15);
    Bfrag2[idx] = (col < OUT_DIM) ? f2bf(W2[k * OUT_DIM + col]) : (unsigned short)0;
  }
}

// Fused partition: packed (ldst<<17|src) by dst>>9  AND  (src&511) by src>>9.
__global__ __launch_bounds__(256) void k_part(const int* __restrict__ src,
                                              const int* __restrict__ dst,
                                              int* __restrict__ gcur,
                                              int* __restrict__ gcur2,
                                              unsigned int* __restrict__ pairs,
                                              unsigned short* __restrict__ spart) {
  __shared__ int scnt[NBKT], soff[NBKT], gbase[NBKT];
  __shared__ int scnt2[NBKT], soff2[NBKT], gbase2[NBKT];
  __shared__ int sc1[256], sc2[256];
  __shared__ unsigned int sord[TILE];           // 16 KB packed pair
  __shared__ unsigned char sordB[TILE];         // 4 KB bucket id
  __shared__ unsigned short sordS[TILE];        // 8 KB local src idx
  __shared__ unsigned char sordSB[TILE];        // 4 KB bucket id
  int tid = threadIdx.x;
  int tileBase = blockIdx.x * TILE;
  int tcnt = N_EDGES - tileBase; if (tcnt > TILE) tcnt = TILE;
  if (tid < NBKT) { scnt[tid] = 0; scnt2[tid] = 0; }
  __syncthreads();
  int s_[EPT], d_[EPT], pos_[EPT], pos2_[EPT];
#pragma unroll
  for (int t = 0; t < EPT; ++t) {
    int idx = tileBase + t * 256 + tid;
    if (idx < N_EDGES) {
      s_[t] = src[idx];
      d_[t] = dst[idx];
      pos_[t]  = atomicAdd(&scnt[d_[t] >> BK_SHIFT], 1);
      pos2_[t] = atomicAdd(&scnt2[s_[t] >> BK_SHIFT], 1);
    }
  }
  __syncthreads();
  // parallel exclusive scan of both count arrays (NBKT <= 256)
  int v1 = (tid < NBKT) ? scnt[tid] : 0;
  int v2 = (tid < NBKT) ? scnt2[tid] : 0;
  sc1[tid] = v1; sc2[tid] = v2;
  __syncthreads();
  for (int o = 1; o < 256; o <<= 1) {
    int x1 = (tid >= o) ? sc1[tid - o] : 0;
    int x2 = (tid >= o) ? sc2[tid - o] : 0;
    __syncthreads();
    sc1[tid] += x1; sc2[tid] += x2;
    __syncthreads();
  }
  if (tid < NBKT) {
    soff[tid]  = sc1[tid] - v1;
    soff2[tid] = sc2[tid] - v2;
    gbase[tid]  = v1 ? atomicAdd(&gcur[tid],  v1) : 0;
    gbase2[tid] = v2 ? atomicAdd(&gcur2[tid], v2) : 0;
  }
  __syncthreads();
#pragma unroll
  for (int t = 0; t < EPT; ++t) {
    int idx = tileBase + t * 256 + tid;
    if (idx < N_EDGES) {
      int b  = d_[t] >> BK_SHIFT;
      int b2 = s_[t] >> BK_SHIFT;
      int p  = soff[b] + pos_[t];
      int p2 = soff2[b2] + pos2_[t];
      sord[p]  = (unsigned)s_[t] | ((unsigned)(d_[t] & 511) << 17);
      sordB[p] = (unsigned char)b;
      sordS[p2]  = (unsigned short)(s_[t] & 511);
      sordSB[p2] = (unsigned char)b2;
    }
  }
  __syncthreads();
  for (int i = tid; i < tcnt; i += 256) {
    int b = sordB[i];
    int g = gbase[b] + (i - soff[b]);
    if (g < ECAP) pairs[(size_t)b * ECAP + g] = sord[i];
  }
  for (int i = tid; i < tcnt; i += 256) {
    int b = sordSB[i];
    int g = gbase2[b] + (i - soff2[b]);
    if (g < ECAP) spart[(size_t)b * ECAP + g] = sordS[i];
  }
}

// Merged: blocks [0,NBKT) build fine CSR; blocks [NBKT,2*NBKT) build norm_src.
__global__ __launch_bounds__(256) void k_csrdeg(const unsigned int* __restrict__ pairs,
                                                const unsigned short* __restrict__ spart,
                                                const int* __restrict__ gcur,
                                                const int* __restrict__ gcur2,
                                                int* __restrict__ startg,
                                                int* __restrict__ cntg,
                                                float* __restrict__ norm_dst,
                                                float* __restrict__ norm_src,
                                                int* __restrict__ esrc) {
  __shared__ int cnt[512];
  __shared__ int off[512];
  __shared__ int cur[512];
  __shared__ int wsum[256];
  __shared__ int esrcL[ECAP];   // 36 KB
  int tid = threadIdx.x;
  if (blockIdx.x >= NBKT) {
    int b = blockIdx.x - NBKT;
    int node0 = b << BK_SHIFT;
    int nNodes = N_NODES - node0; if (nNodes > 512) nNodes = 512;
    int E = gcur2[b]; if (E > ECAP) E = ECAP;
    cnt[tid] = 0; cnt[tid + 256] = 0;
    __syncthreads();
    const unsigned short* sp = spart + (size_t)b * ECAP;
    for (int i = tid; i < E; i += 256) atomicAdd(&cnt[sp[i]], 1);
    __syncthreads();
    for (int j = tid; j < nNodes; j += 256) {
      int c = cnt[j];
      norm_src[node0 + j] = rsqrtf((float)(c < 1 ? 1 : c));
    }
    return;
  }
  int b = blockIdx.x;
  int node0 = b << BK_SHIFT;
  int nNodes = N_NODES - node0; if (nNodes > 512) nNodes = 512;
  int E = gcur[b]; if (E > ECAP) E = ECAP;
  cnt[tid] = 0; cnt[tid + 256] = 0;
  __syncthreads();
  const unsigned int* pp = pairs + (size_t)b * ECAP;
  for (int i = tid; i < E; i += 256) atomicAdd(&cnt[pp[i] >> 17], 1);
  __syncthreads();
  int v0 = cnt[tid * 2], v1 = cnt[tid * 2 + 1];
  int s = v0 + v1;
  wsum[tid] = s; __syncthreads();
  for (int o = 1; o < 256; o <<= 1) {
    int x = (tid >= o) ? wsum[tid - o] : 0;
    __syncthreads();
    wsum[tid] += x;
    __syncthreads();
  }
  int excl = wsum[tid] - s;
  off[tid * 2] = excl;     cur[tid * 2] = excl;
  off[tid * 2 + 1] = excl + v0; cur[tid * 2 + 1] = excl + v0;
  __syncthreads();
  for (int i = tid; i < E; i += 256) {
    unsigned p = pp[i];
    int pos = atomicAdd(&cur[p >> 17], 1);
    esrcL[pos] = (int)(p & 0x1FFFFu);
  }
  __syncthreads();
  int base = b * ECAP;
  for (int i = tid; i < E; i += 256) esrc[base + i] = esrcL[i];
  for (int j = tid; j < nNodes; j += 256) {
    int c = cnt[j];
    startg[node0 + j] = base + off[j];
    cntg[node0 + j] = c;
    norm_dst[node0 + j] = rsqrtf((float)(c < 1 ? 1 : c));
  }
}

// MFMA GEMM1: t1[row][0..63] = bf16( (feats[row][:] @ W1) * norm_src[row] )
__global__ __launch_bounds__(256) void k_gemm1_mfma(
    const float* __restrict__ feats, const uint4* __restrict__ Bfrag1,
    const float* __restrict__ norm_src, __hip_bfloat16* __restrict__ t1) {
  int tid = threadIdx.x;
  int w = tid >> 6, lane = tid & 63;
  int row0 = blockIdx.x * 64 + w * 16;
  int arow = row0 + (lane & 15);
  int arowc = arow < N_NODES ? arow : N_NODES - 1;
  int half = lane >> 4;

  const float4* fr = (const float4*)(feats + (size_t)arowc * IN_DIM);
  f32x4 acc[4] = {{0.f,0.f,0.f,0.f},{0.f,0.f,0.f,0.f},{0.f,0.f,0.f,0.f},{0.f,0.f,0.f,0.f}};
#pragma unroll
  for (int ks = 0; ks < 4; ++ks) {
    float4 p0 = fr[ks * 8 + 2 * half];
    float4 p1 = fr[ks * 8 + 2 * half + 1];
    short8 a;
    a[0] = (short)f2bf(p0.x); a[1] = (short)f2bf(p0.y);
    a[2] = (short)f2bf(p0.z); a[3] = (short)f2bf(p0.w);
    a[4] = (short)f2bf(p1.x); a[5] = (short)f2bf(p1.y);
    a[6] = (short)f2bf(p1.z); a[7] = (short)f2bf(p1.w);
#pragma unroll
    for (int nt = 0; nt < 4; ++nt) {
      uint4 bu = Bfrag1[(ks * 4 + nt) * 64 + lane];
      short8 b = *(const short8*)&bu;
      acc[nt] = __builtin_amdgcn_mfma_f32_16x16x32_bf16(a, b, acc[nt], 0, 0, 0);
    }
  }
  int col = lane & 15;
  int rbase = row0 + half * 4;
#pragma unroll
  for (int r = 0; r < 4; ++r) {
    int grow = rbase + r;
    if (grow < N_NODES) {
      float ns = norm_src[grow];
#pragma unroll
      for (int nt = 0; nt < 4; ++nt) {
        unsigned short h = f2bf(acc[nt][r] * ns);
        *((unsigned short*)t1 + (size_t)grow * HID_DIM + nt * 16 + col) = h;
      }
    }
  }
}

// Fused layer-1 gather + layer-2 GEMM.
// 32 nodes/block, 8 lanes per node, each lane owns 8 bf16 cols (uint4 = 16 B).
__global__ __launch_bounds__(256) void k_agg1g2(
    const uint4* __restrict__ t1, const int* __restrict__ startg,
    const int* __restrict__ cntg, const int* __restrict__ esrc,
    const float* __restrict__ norm_dst, const float* __restrict__ norm_src,
    const float4* __restrict__ b1v, const uint4* __restrict__ Bfrag2,
    float4* __restrict__ out1, __hip_bfloat16* __restrict__ t2) {
  __shared__ unsigned short h1s[32][64];   // 4 KB bf16 A-tile
  int tid = threadIdx.x;
  int g = tid >> 3, q = tid & 7;
  int n = blockIdx.x * 32 + g;          // 100000 = 3125*32 exact
  int s0 = startg[n];
  int c  = cntg[n];
  const int* bk = esrc + s0;
  float a0 = 0.f, a1 = 0.f, a2 = 0.f, a3 = 0.f;
  float a4 = 0.f, a5 = 0.f, a6 = 0.f, a7 = 0.f;
  for (int i = 0; i < c; i += 8) {
#pragma unroll
    for (int t = 0; t < 8; ++t) {
      int ii = i + t;
      bool ok = ii < c;
      int s = bk[ok ? ii : 0];
      uint4 v = t1[(size_t)s * 8 + q];
      unsigned vx = ok ? v.x : 0u;
      unsigned vy = ok ? v.y : 0u;
      unsigned vz = ok ? v.z : 0u;
      unsigned vw = ok ? v.w : 0u;
      a0 += bf2f(vx & 0xffffu); a1 += bf2f(vx >> 16);
      a2 += bf2f(vy & 0xffffu); a3 += bf2f(vy >> 16);
      a4 += bf2f(vz & 0xffffu); a5 += bf2f(vz >> 16);
      a6 += bf2f(vw & 0xffffu); a7 += bf2f(vw >> 16);
    }
  }
  float nd = norm_dst[n];
  float4 bb0 = b1v[q * 2];
  float4 bb1 = b1v[q * 2 + 1];
  float h0 = fmaxf(a0 * nd + bb0.x, 0.f);
  float h1 = fmaxf(a1 * nd + bb0.y, 0.f);
  float h2 = fmaxf(a2 * nd + bb0.z, 0.f);
  float h3 = fmaxf(a3 * nd + bb0.w, 0.f);
  float h4 = fmaxf(a4 * nd + bb1.x, 0.f);
  float h5 = fmaxf(a5 * nd + bb1.y, 0.f);
  float h6 = fmaxf(a6 * nd + bb1.z, 0.f);
  float h7 = fmaxf(a7 * nd + bb1.w, 0.f);
  out1[(size_t)n * 16 + q * 2]     = make_float4(h0, h1, h2, h3);
  out1[(size_t)n * 16 + q * 2 + 1] = make_float4(h4, h5, h6, h7);
  float ns = norm_src[n];
  uint4 pk;
  pk.x = (unsigned)f2bf(h0 * ns) | ((unsigned)f2bf(h1 * ns) << 16);
  pk.y = (unsigned)f2bf(h2 * ns) | ((unsigned)f2bf(h3 * ns) << 16);
  pk.z = (unsigned)f2bf(h4 * ns) | ((unsigned)f2bf(h5 * ns) << 16);
  pk.w = (unsigned)f2bf(h6 * ns) | ((unsigned)f2bf(h7 * ns) << 16);
  *(uint4*)&h1s[g][q * 8] = pk;
  __syncthreads();
  if (tid < 128) {
    int wave = tid >> 6;
    int lane = tid & 63;
    int r = lane & 15, half = lane >> 4;
    int row = wave * 16 + r;
    f32x4 acc[3] = {{0.f,0.f,0.f,0.f},{0.f,0.f,0.f,0.f},{0.f,0.f,0.f,0.f}};
#pragma unroll
    for (int ks = 0; ks < 2; ++ks) {
      short8 a = *(const short8*)&h1s[row][ks * 32 + 8 * half];
#pragma unroll
      for (int nt = 0; nt < 3; ++nt) {
        uint4 bu = Bfrag2[(ks * 3 + nt) * 64 + lane];
        short8 b = *(const short8*)&bu;
        acc[nt] = __builtin_amdgcn_mfma_f32_16x16x32_bf16(a, b, acc[nt], 0, 0, 0);
      }
    }
    int col = lane & 15;
#pragma unroll
    for (int r2 = 0; r2 < 4; ++r2) {
      int node = blockIdx.x * 32 + wave * 16 + half * 4 + r2;
#pragma unroll
      for (int nt = 0; nt < 3; ++nt) {
        int j = nt * 16 + col;
        if (j < OUT_DIM)
          *((unsigned short*)t2 + (size_t)node * OUT_DIM + j) = f2bf(acc[nt][r2]);
      }
    }
  }
}

// Layer-2 gather: 5 lanes per node, each lane owns 8 bf16 cols (uint4 = 16 B).
__global__ __launch_bounds__(256) void k_agg2(
    const uint4* __restrict__ t2, const int* __restrict__ startg,
    const int* __restrict__ cntg, const int* __restrict__ esrc,
    const float* __restrict__ norm_dst, const float* __restrict__ b2,
    float4* __restrict__ out2) {
  int idx = blockIdx.x * blockDim.x + threadIdx.x;
  int n = idx / 5;
  int q = idx - n * 5;
  if (n >= N_NODES) return;
  int s0 = startg[n];
  int c  = cntg[n];
  const int* bk = esrc + s0;
  float a0 = 0.f, a1 = 0.f, a2 = 0.f, a3 = 0.f;
  float a4 = 0.f, a5 = 0.f, a6 = 0.f, a7 = 0.f;
  for (int i = 0; i < c; i += 8) {
#pragma unroll
    for (int t = 0; t < 8; ++t) {
      int ii = i + t;
      bool ok = ii < c;
      int s = bk[ok ? ii : 0];
      uint4 v = t2[(size_t)s * 5 + q];
      unsigned vx = ok ? v.x : 0u;
      unsigned vy = ok ? v.y : 0u;
      unsigned vz = ok ? v.z : 0u;
      unsigned vw = ok ? v.w : 0u;
      a0 += bf2f(vx & 0xffffu); a1 += bf2f(vx >> 16);
      a2 += bf2f(vy & 0xffffu); a3 += bf2f(vy >> 16);
      a4 += bf2f(vz & 0xffffu); a5 += bf2f(vz >> 16);
      a6 += bf2f(vw & 0xffffu); a7 += bf2f(vw >> 16);
    }
  }
  float nd = norm_dst[n];
  float4 bb0 = *(const float4*)(b2 + q * 8);
  float4 bb1 = *(const float4*)(b2 + q * 8 + 4);
  out2[(size_t)n * 10 + q * 2] =
      make_float4(a0 * nd + bb0.x, a1 * nd + bb0.y, a2 * nd + bb0.z, a3 * nd + bb0.w);
  out2[(size_t)n * 10 + q * 2 + 1] =
      make_float4(a4 * nd + bb1.x, a5 * nd + bb1.y, a6 * nd + bb1.z, a7 * nd + bb1.w);
}

extern "C" void kernel_launch(void* const* d_in, const int* in_sizes, int n_in,
                              void* d_out, int out_size, void* d_ws, size_t ws_size,
                              hipStream_t stream) {
  const float* feats = (const float*)d_in[0];
  const float* W1    = (const float*)d_in[1];
  const float* b1    = (const float*)d_in[2];
  const float* W2    = (const float*)d_in[3];
  const float* b2    = (const float*)d_in[4];
  const int*   src   = (const int*)d_in[5];
  const int*   dst   = (const int*)d_in[6];

  float* out  = (float*)d_out;
  float* out1 = out;                                  // [N, 64]
  float* out2 = out + (size_t)N_NODES * HID_DIM;      // [N, 40]

  __hip_bfloat16* t1 = (__hip_bfloat16*)d_ws;                 // 12.8 MB
  __hip_bfloat16* t2 = t1 + (size_t)N_NODES * HID_DIM;        //  8.0 MB
  unsigned int* pairs = (unsigned int*)(t2 + (size_t)N_NODES * OUT_DIM);   // 7.22 MB
  unsigned short* spart = (unsigned short*)(pairs + (size_t)NBKT * ECAP);  // 3.61 MB
  int* esrc   = (int*)(spart + (size_t)NBKT * ECAP);          // 7.22 MB
  unsigned short* Bfrag1 = (unsigned short*)(esrc + (size_t)NBKT * ECAP);  // 16 KB
  unsigned short* Bfrag2 = Bfrag1 + 4 * 4 * 64 * 8;           // 6 KB
  int* startg = (int*)(Bfrag2 + 2 * 3 * 64 * 8);              // [N]
  int* cntg   = startg + N_NODES;                             // [N]
  float* norm_src = (float*)(cntg + N_NODES);                 // [N]
  float* norm_dst = norm_src + N_NODES;                       // [N]
  int* gcur  = (int*)(norm_dst + N_NODES);                    // [2*NBKT]
  int* gcur2 = gcur + NBKT;

  k_init<<<16, 256, 0, stream>>>(W1, W2, Bfrag1, Bfrag2, gcur);
  k_part<<<NTILES, 256, 0, stream>>>(src, dst, gcur, gcur2, pairs, spart);
  k_csrdeg<<<2 * NBKT, 256, 0, stream>>>(pairs, spart, gcur, gcur2,
                                         startg, cntg, norm_dst, norm_src, esrc);

  // layer 1 GEMM
  k_gemm1_mfma<<<GEMM_BLK, 256, 0, stream>>>(feats, (const uint4*)Bfrag1, norm_src, t1);
  // layer-1 aggregate + fused layer-2 GEMM (32 nodes/block)
  k_agg1g2<<<N_NODES / 32, 256, 0, stream>>>((const uint4*)t1, startg, cntg, esrc,
                                             norm_dst, norm_src, (const float4*)b1,
                                             (const uint4*)Bfrag2, (float4*)out1, t2);
  // layer-2 aggregate (5 lanes/node)
  k_agg2<<<(N_NODES * 5 + 255) / 256, 256, 0, stream>>>((const uint4*)t2, startg, cntg, esrc,
                                                        norm_dst, b2, (float4*)out2);
}